// Round 9
// baseline (158.444 us; speedup 1.0000x reference)
//
#include <hip/hip_runtime.h>
#include <hip/hip_fp16.h>
#include <math.h>

typedef __attribute__((ext_vector_type(8))) short short8;
typedef __attribute__((ext_vector_type(16))) float floatx16;
typedef __attribute__((ext_vector_type(2))) __bf16 bf16x2;
typedef __attribute__((ext_vector_type(2))) unsigned int uint2v;

namespace {
constexpr int Bn = 8;
constexpr int Sn = 2048;
constexpr int Dn = 128;
constexpr int BQ = 256;                // queries per block (8 waves x 32)  [R9]
constexpr int BK = 64;                 // keys per tile
constexpr int QT = Sn / BQ;            // 8 query tiles
constexpr int NKB = Sn / BK;           // 32 (max tiles; compacted count is dynamic)
constexpr int ROWS = Bn * Sn;          // 16384
constexpr int NSPLIT = 8;              // grid 512 blocks(512thr) = 2 blocks/CU = 16 waves/CU
constexpr float SC2 = 0.12753102063642597f;  // (1/sqrt(128)) * log2(e)
constexpr float DEFER_THR = 8.0f;      // log2-domain defer-max threshold (T13)
constexpr int TILE_USH = BK * Dn;      // 8192 ushorts = 16 KB tile
}

#if __has_builtin(__builtin_amdgcn_exp2f)
#define EXP2(x) __builtin_amdgcn_exp2f(x)
#else
#define EXP2(x) exp2f(x)
#endif

__device__ __forceinline__ unsigned short f2bf(float x) {
  union { float f; unsigned u; } a; a.f = x;
  unsigned r = a.u + 0x7fffu + ((a.u >> 16) & 1u);   // RNE
  return (unsigned short)(r >> 16);
}

// HW packed convert: 2 floats -> bf16x2 (v_cvt_pk_bf16_f32)
__device__ __forceinline__ unsigned pack2bf(float x, float y) {
  union { bf16x2 b; unsigned u; } c;
  c.b[0] = (__bf16)x; c.b[1] = (__bf16)y;
  return c.u;
}

// lane[i] <-> lane[i+32] half exchange; returns {r0, r1}:
//   r0[lane<32]=a(own)          r0[lane>=32]=b(from lane-32)
//   r1[lane<32]=a(from lane+32) r1[lane>=32]=b(own)
__device__ __forceinline__ uint2v pl32swap(unsigned a, unsigned b, int h) {
#if __has_builtin(__builtin_amdgcn_permlane32_swap)
  (void)h;
  return __builtin_amdgcn_permlane32_swap(a, b, false, false);
#else
  unsigned ax = __shfl_xor((int)a, 32);
  unsigned bx = __shfl_xor((int)b, 32);
  uint2v r;
  r[0] = h ? bx : a;
  r[1] = h ? b : ax;
  return r;
#endif
}

__device__ __forceinline__ void gl_lds16(const void* g, void* l, int lane) {
#if __has_builtin(__builtin_amdgcn_global_load_lds)
  (void)lane;
  __builtin_amdgcn_global_load_lds((const __attribute__((address_space(1))) unsigned int*)g,
                                   (__attribute__((address_space(3))) unsigned int*)l, 16, 0, 0);
#else
  *(float4*)((char*)l + lane * 16) = *(const float4*)g;
#endif
}

// ---------------- mask scan (8 blocks x 256 thr, one block per batch):
// layout sniff + prefix scan of unmasked keys -> compacted index list
// idx[b][0..cnt), cnt[b]. Bias derived from cnt in-register in attn_fwd.
__global__ __launch_bounds__(256)
void mask_scan(const unsigned char* __restrict__ mraw,
               unsigned short* __restrict__ idxg, int* __restrict__ cntg) {
  __shared__ int sc[256];
  const int b = blockIdx.x;
  const int t = threadIdx.x;

  // sniff dtype of the mask buffer (same first 1 KB for all blocks -> consistent)
  unsigned wv = ((const unsigned int*)mraw)[t];
  int any1  = __syncthreads_or((wv & 0x0000ff00u) ? 1 : 0);
  int any23 = __syncthreads_or((wv & 0xffff0000u) ? 1 : 0);
  const int mlayout = any1 ? 1 : (any23 ? 2 : 0);

  const int s0 = t * 8;              // 8 consecutive key positions per thread
  const int gbase = b * Sn + s0;
  bool ms[8];
  if (mlayout == 1) {
    #pragma unroll
    for (int i = 0; i < 8; ++i) ms[i] = mraw[gbase + i] != 0;
  } else if (mlayout == 2) {
    const float* mf = (const float*)mraw;
    #pragma unroll
    for (int i = 0; i < 8; ++i) ms[i] = mf[gbase + i] != 0.0f;
  } else {
    const int* mi = (const int*)mraw;
    #pragma unroll
    for (int i = 0; i < 8; ++i) ms[i] = mi[gbase + i] != 0;
  }

  int c = 0;
  #pragma unroll
  for (int i = 0; i < 8; ++i) c += ms[i] ? 0 : 1;
  sc[t] = c;
  __syncthreads();
  for (int off = 1; off < 256; off <<= 1) {      // Hillis-Steele inclusive scan
    int v = (t >= off) ? sc[t - off] : 0;
    __syncthreads();
    sc[t] += v;
    __syncthreads();
  }
  const int incl = sc[t];
  const int total = sc[255];
  int pos = incl - c;                            // exclusive prefix
  #pragma unroll
  for (int i = 0; i < 8; ++i)
    if (!ms[i]) idxg[b * Sn + (pos++)] = (unsigned short)(s0 + i);
  if (t == 0) cntg[b] = total;
}

// ---------------- pre-pass (1024 blocks x 256 thr, 16 compacted slots each):
// gather unmasked K/V rows through idx; K -> bf16 swizzled tiles
// [key][oct(d>>3)^(key&7)], V -> bf16 transposed tiles [d][oct(key>>3)^(d&7)].
// Padding slots (cnt..padded) are ZEROED. Blocks beyond padded end early-out.
__global__ __launch_bounds__(256)
void prep(const float* __restrict__ kg, const float* __restrict__ vg,
          const unsigned short* __restrict__ idxg, const int* __restrict__ cntg,
          unsigned short* __restrict__ Kpg, unsigned short* __restrict__ Vpg) {
  __shared__ __align__(16) float Vf[16 * 136];
  const int p = blockIdx.x;
  const int b = p >> 7, qq = p & 127;
  const int kb = qq >> 2, k16 = qq & 3;
  const int t = threadIdx.x;

  const int cnt = cntg[b];
  const int padded = (cnt + 63) & ~63;
  const int slot0 = kb * 64 + k16 * 16;
  if (slot0 >= padded) return;                   // block-uniform

  const int j  = t >> 4;
  const int o8 = t & 15;
  const int sl = slot0 + j;
  const bool real = sl < cnt;

  float4 a, bq, va, vb;
  if (real) {
    const int srow = idxg[b * Sn + sl];
    const size_t base = ((size_t)(b * Sn + srow)) * 32 + o8 * 2;
    a  = ((const float4*)kg)[base]; bq = ((const float4*)kg)[base + 1];
    va = ((const float4*)vg)[base]; vb = ((const float4*)vg)[base + 1];
  } else {
    a = bq = va = vb = make_float4(0.f, 0.f, 0.f, 0.f);
  }

  {
    union { unsigned u[4]; short8 s8; } pk;
    pk.u[0] = pack2bf(a.x, a.y);   pk.u[1] = pack2bf(a.z, a.w);
    pk.u[2] = pack2bf(bq.x, bq.y); pk.u[3] = pack2bf(bq.z, bq.w);
    const int jl = k16 * 16 + j;
    *(short8*)(Kpg + (size_t)(b * NKB + kb) * TILE_USH + jl * 128 + ((o8 ^ (jl & 7)) * 8)) = pk.s8;
  }
  {
    *(float4*)&Vf[j * 136 + o8 * 8]     = va;
    *(float4*)&Vf[j * 136 + o8 * 8 + 4] = vb;
  }
  __syncthreads();
  {
    const int d = t >> 1, h = t & 1;
    union { unsigned u[4]; short8 s8; } pv;
    #pragma unroll
    for (int i = 0; i < 4; ++i)
      pv.u[i] = pack2bf(Vf[(h * 8 + 2 * i) * 136 + d], Vf[(h * 8 + 2 * i + 1) * 136 + d]);
    const int og = k16 * 2 + h;
    *(short8*)(Vpg + (size_t)(b * NKB + kb) * TILE_USH + d * 64 + ((og ^ (d & 7)) * 8)) = pv.s8;
  }
}

// ---- staging helper: one of 8 waves stages its 2 KB eighth of a 16 KB tile ----
__device__ __forceinline__ void stage_tile(const char* gsrc, char* ldst,
                                           int stagebase, int L) {
  #pragma unroll
  for (int i = 0; i < 2; ++i) {
    const int off = stagebase + i * 1024;
    gl_lds16(gsrc + off + L * 16, ldst + off, L);
  }
}

// ---------------- main flash kernel over COMPACTED keys.
// R9: TLP doubled. All prior structures ran 2 waves/SIMD (2 blocks/CU x 4
// waves) and attn stayed ~43-56us with every pipe <15% busy — latency-bound
// with half the latency-hiding capacity unused (VGPR=128 supports 4
// waves/SIMD). Re-tiled: 512-thread blocks (8 waves, BQ=256), NSPLIT=8 ->
// grid 512 blocks = 2 blocks/CU = 16 waves/CU = 4 waves/SIMD
// (__launch_bounds__(512,4) caps VGPR at 128, which the body already fits).
// LDS 64 KB: K/V double-buffered, stage depth 1, counted vmcnt (T3/T4):
//   per tile: issue V(i+1),K(i+1) -> s_waitcnt vmcnt(4|0) -> s_barrier ->
//   compute from LDS -> s_barrier.
// Race safety: stage(i+1) writes buf (i+1)&1, whose last readers (tile i-1)
// all passed B2(i-1) before this wave could issue (program order).
template<int SPLIT, bool DIRECT>
__global__ __launch_bounds__(512, 4)
void attn_fwd(const float* __restrict__ qg,
              const unsigned short* __restrict__ Kpg,
              const unsigned short* __restrict__ Vpg,
              const int* __restrict__ cntg,
              float* __restrict__ outg, __half* __restrict__ Op,
              float* __restrict__ Mp, float* __restrict__ Lp) {
  __shared__ __align__(16) unsigned short Khi[2][TILE_USH];  // 32768 B
  __shared__ __align__(16) unsigned short Vt[2][TILE_USH];   // 32768 B
  // total 65536 B -> 2 blocks/CU

  const int tid = threadIdx.x;
  const int bid = blockIdx.x;
  const int b   = bid & 7;                       // batch -> XCD swizzle
  const int q0  = ((bid >> 3) & (QT - 1)) * BQ;
  const int s   = bid >> 6;                      // split index (0 when SPLIT==1)
  const int w   = tid >> 6;                      // wave 0..7
  const int L   = tid & 63;
  const int q   = L & 31;                        // query within wave
  const int h   = L >> 5;                        // k-half selector
  const int sw  = q & 7;                         // octet XOR swizzle key

  const int cnt = cntg[b];
  const int nt  = (cnt + 63) >> 6;               // compacted tile count
  const int kb0 = (s * nt) / SPLIT;
  const int kbN = ((s + 1) * nt) / SPLIT;
  const int T   = kbN - kb0;

  const int row = b * Sn + q0 + w * 32 + q;

  if (T <= 0) {                                  // empty split: zero partials
    if constexpr (DIRECT) {
      float* orow = outg + (size_t)row * Dn;
      float4 z = make_float4(0.f, 0.f, 0.f, 0.f);
      #pragma unroll
      for (int dg = 0; dg < 4; ++dg)
        #pragma unroll
        for (int ro = 0; ro < 4; ++ro) *(float4*)&orow[dg * 32 + 8 * ro + 4 * h] = z;
    } else {
      __half* orow = Op + ((size_t)s * ROWS + row) * Dn;
      uint2 z; z.x = 0u; z.y = 0u;
      #pragma unroll
      for (int dg = 0; dg < 4; ++dg)
        #pragma unroll
        for (int ro = 0; ro < 4; ++ro) *(uint2*)&orow[dg * 32 + 8 * ro + 4 * h] = z;
      if (h == 0) { Mp[s * ROWS + row] = -INFINITY; Lp[s * ROWS + row] = 0.0f; }
    }
    return;
  }

  const char* ktile = (const char*)(Kpg + (size_t)b * NKB * TILE_USH);
  const char* vtile = (const char*)(Vpg + (size_t)b * NKB * TILE_USH);
  const int stagebase = w * 2048;                // wave's eighth of a 16 KB tile

  // Q B-fragments: lane holds Q[row q][d = kstep*16 + h*8 + j], hi/lo split
  short8 qh[8], ql[8];
  {
    const float* qrow = qg + (size_t)row * Dn;
    #pragma unroll
    for (int kstep = 0; kstep < 8; ++kstep) {
      float4 f0 = *(const float4*)(qrow + kstep * 16 + h * 8);
      float4 f1 = *(const float4*)(qrow + kstep * 16 + h * 8 + 4);
      float xs[8] = {f0.x, f0.y, f0.z, f0.w, f1.x, f1.y, f1.z, f1.w};
      #pragma unroll
      for (int j = 0; j < 8; ++j) {
        unsigned short hi = f2bf(xs[j]);
        union { unsigned u; float f; } hv; hv.u = ((unsigned)hi) << 16;
        qh[kstep][j] = (short)hi;
        ql[kstep][j] = (short)f2bf(xs[j] - hv.f);
      }
    }
  }

  float m_i = -INFINITY, l_i = 0.0f;
  float mtrue = -INFINITY;
  floatx16 O32[4];
  #pragma unroll
  for (int dg = 0; dg < 4; ++dg)
    #pragma unroll
    for (int r = 0; r < 16; ++r) O32[dg][r] = 0.0f;

  // ---- prologue: issue V(0), K(0) (order matters for vmcnt counts) ----
  stage_tile(vtile + (size_t)kb0 * (TILE_USH * 2), (char*)Vt[0], stagebase, L);
  stage_tile(ktile + (size_t)kb0 * (TILE_USH * 2), (char*)Khi[0], stagebase, L);

  for (int kb = kb0; kb < kbN; ++kb) {
    const int i = kb - kb0;

    // ---- issue next stages: V(i+1) then K(i+1) into the other buffers ----
    const bool hasNext = (kb + 1 < kbN);
    if (hasNext) {
      stage_tile(vtile + (size_t)(kb + 1) * (TILE_USH * 2),
                 (char*)Vt[(i + 1) & 1], stagebase, L);
      stage_tile(ktile + (size_t)(kb + 1) * (TILE_USH * 2),
                 (char*)Khi[(i + 1) & 1], stagebase, L);
    }

    // ---- counted wait: tile-i data (V(i),K(i)) done; next stages stay in flight
    if (hasNext) asm volatile("s_waitcnt vmcnt(4)" ::: "memory");
    else         asm volatile("s_waitcnt vmcnt(0)" ::: "memory");
    __builtin_amdgcn_s_barrier();                // B1: tile-i K/V ready (all waves)
    asm volatile("" ::: "memory");

    const unsigned short* Kc = Khi[i & 1];
    const unsigned short* Vc = Vt[i & 1];

    // ---- S^T = K * Q^T : 2 key-groups x 8 ksteps, hi+lo (K from LDS) ----
    floatx16 sS[2];
    #pragma unroll
    for (int kg = 0; kg < 2; ++kg)
      #pragma unroll
      for (int r = 0; r < 16; ++r) sS[kg][r] = 0.0f;
    #pragma unroll
    for (int kstep = 0; kstep < 8; ++kstep) {
      const int ko = ((kstep * 2 + h) ^ sw) * 8;
      #pragma unroll
      for (int kg = 0; kg < 2; ++kg) {
        short8 kf = *(const short8*)&Kc[(kg * 32 + q) * 128 + ko];
        sS[kg] = __builtin_amdgcn_mfma_f32_32x32x16_bf16(kf, qh[kstep], sS[kg], 0, 0, 0);
        sS[kg] = __builtin_amdgcn_mfma_f32_32x32x16_bf16(kf, ql[kstep], sS[kg], 0, 0, 0);
      }
    }

    // ---- softmax: scale (+ in-register bias on the last, partial tile) ----
    if ((kb + 1) * BK <= cnt) {                  // full tile (wave-uniform)
      #pragma unroll
      for (int kg = 0; kg < 2; ++kg)
        #pragma unroll
        for (int r = 0; r < 16; ++r) sS[kg][r] *= SC2;
    } else {
      #pragma unroll
      for (int kg = 0; kg < 2; ++kg)
        #pragma unroll
        for (int r = 0; r < 16; ++r) {
          const int key = kb * BK + kg * 32 + ((r & 3) + 8 * (r >> 2)) + 4 * h;
          sS[kg][r] = fmaf(sS[kg][r], SC2, (key < cnt) ? 0.0f : -1e30f);
        }
    }
    float mxp[4] = {-INFINITY, -INFINITY, -INFINITY, -INFINITY};
    #pragma unroll
    for (int kg = 0; kg < 2; ++kg)
      #pragma unroll
      for (int r = 0; r < 16; ++r) mxp[r & 3] = fmaxf(mxp[r & 3], sS[kg][r]);
    float mx = fmaxf(fmaxf(mxp[0], mxp[1]), fmaxf(mxp[2], mxp[3]));
    mx = fmaxf(mx, __shfl_xor(mx, 32));
    mtrue = fmaxf(mtrue, mx);

    float mnew;
    if (__all(mx <= m_i + DEFER_THR)) {
      mnew = m_i;                       // T13: defer; P bounded by 2^THR
    } else {
      mnew = fmaxf(m_i, mx);
      const float alpha = EXP2(m_i - mnew);   // 0 when m_i == -inf
      l_i *= alpha;
      #pragma unroll
      for (int dg = 0; dg < 4; ++dg)
        #pragma unroll
        for (int r = 0; r < 16; ++r) O32[dg][r] *= alpha;
    }

    float rsp[4] = {0.f, 0.f, 0.f, 0.f};
    #pragma unroll
    for (int kg = 0; kg < 2; ++kg)
      #pragma unroll
      for (int r = 0; r < 16; ++r) {
        float e = EXP2(sS[kg][r] - mnew);
        sS[kg][r] = e;
        rsp[r & 3] += e;
      }
    float rs = (rsp[0] + rsp[1]) + (rsp[2] + rsp[3]);
    rs += __shfl_xor(rs, 32);
    l_i += rs;
    m_i = mnew;

    // ---- T12: P -> bf16 in-register, half-exchange via permlane32_swap ----
    unsigned xw[2][4][2];
    #pragma unroll
    for (int kg = 0; kg < 2; ++kg)
      #pragma unroll
      for (int m = 0; m < 4; ++m) {
        xw[kg][m][0] = pack2bf(sS[kg][4 * m + 0], sS[kg][4 * m + 1]);
        xw[kg][m][1] = pack2bf(sS[kg][4 * m + 2], sS[kg][4 * m + 3]);
      }
    unsigned pfw[4][4];
    #pragma unroll
    for (int kg = 0; kg < 2; ++kg)
      #pragma unroll
      for (int j = 0; j < 2; ++j)
        #pragma unroll
        for (int c2 = 0; c2 < 2; ++c2) {
          uint2v r = pl32swap(xw[kg][2 * j][c2], xw[kg][2 * j + 1][c2], h);
          pfw[kg * 2 + j][c2]     = r[0];   // keys 8s+{2c2,2c2+1}
          pfw[kg * 2 + j][2 + c2] = r[1];   // keys 8s+4+{2c2,2c2+1}
        }

    // ---- O^T += V^T * P^T : 4 ksteps x 4 d-groups (V from LDS) ----
    #pragma unroll
    for (int k2 = 0; k2 < 4; ++k2) {
      const int ko = ((k2 * 2 + h) ^ sw) * 8;
      union { unsigned u[4]; short8 s8; } pw;
      pw.u[0] = pfw[k2][0]; pw.u[1] = pfw[k2][1];
      pw.u[2] = pfw[k2][2]; pw.u[3] = pfw[k2][3];
      #pragma unroll
      for (int dg = 0; dg < 4; ++dg) {
        short8 vf = *(const short8*)&Vc[(dg * 32 + q) * 64 + ko];
        O32[dg] = __builtin_amdgcn_mfma_f32_32x32x16_bf16(vf, pw.s8, O32[dg], 0, 0, 0);
      }
    }

    asm volatile("" ::: "memory");
    __builtin_amdgcn_s_barrier();                // B2: all reads of tile-i done
  }

  // ---- epilogue: lane holds out^T[d = dg*32+(r&3)+8*(r>>2)+4h][q] ----
  if constexpr (DIRECT) {
    const float inv = 1.0f / l_i;
    float* orow = outg + (size_t)row * Dn;
    #pragma unroll
    for (int dg = 0; dg < 4; ++dg)
      #pragma unroll
      for (int ro = 0; ro < 4; ++ro) {
        float4 f = make_float4(O32[dg][4 * ro] * inv,     O32[dg][4 * ro + 1] * inv,
                               O32[dg][4 * ro + 2] * inv, O32[dg][4 * ro + 3] * inv);
        *(float4*)&orow[dg * 32 + 8 * ro + 4 * h] = f;
      }
  } else {
    const float fin = EXP2(m_i - mtrue);   // <= 1; ==1 when never deferred
    __half* orow = Op + ((size_t)s * ROWS + row) * Dn;
    #pragma unroll
    for (int dg = 0; dg < 4; ++dg)
      #pragma unroll
      for (int ro = 0; ro < 4; ++ro) {
        union { __half2 h2[2]; uint2 u; } pk;
        pk.h2[0] = __floats2half2_rn(O32[dg][4 * ro] * fin,     O32[dg][4 * ro + 1] * fin);
        pk.h2[1] = __floats2half2_rn(O32[dg][4 * ro + 2] * fin, O32[dg][4 * ro + 3] * fin);
        *(uint2*)&orow[dg * 32 + 8 * ro + 4 * h] = pk.u;
      }
    if (h == 0) {
      Mp[s * ROWS + row] = mtrue;
      Lp[s * ROWS + row] = l_i * fin;
    }
  }
}

// Merge NSPLIT fp16 partials (m in log2 domain): O = sum O_s*2^{m_s-m}; out = O/l.
// Empty splits carry Mp=-inf, Lp=0, Op=0 -> wgt 0, contribute nothing.
__global__ __launch_bounds__(256)
void attn_combine(const __half* __restrict__ Op, const float* __restrict__ Mp,
                  const float* __restrict__ Lp, float4* __restrict__ out4) {
  const int gid = blockIdx.x * 256 + threadIdx.x;
  const int row = gid >> 5;
  const int c4  = gid & 31;
  float ms[NSPLIT];
  float m = -INFINITY;
  #pragma unroll
  for (int s = 0; s < NSPLIT; ++s) { ms[s] = Mp[s * ROWS + row]; m = fmaxf(m, ms[s]); }
  float l = 0.0f;
  float4 acc = make_float4(0.f, 0.f, 0.f, 0.f);
  #pragma unroll
  for (int s = 0; s < NSPLIT; ++s) {
    float wgt = EXP2(ms[s] - m);
    l = fmaf(Lp[s * ROWS + row], wgt, l);
    union { uint2 u; __half2 h2[2]; } pk;
    pk.u = ((const uint2*)Op)[(size_t)(s * ROWS + row) * 32 + c4];
    float2 f0 = __half22float2(pk.h2[0]);
    float2 f1 = __half22float2(pk.h2[1]);
    acc.x = fmaf(f0.x, wgt, acc.x);
    acc.y = fmaf(f0.y, wgt, acc.y);
    acc.z = fmaf(f1.x, wgt, acc.z);
    acc.w = fmaf(f1.y, wgt, acc.w);
  }
  float inv = 1.0f / l;
  out4[(size_t)row * 32 + c4] = make_float4(acc.x * inv, acc.y * inv, acc.z * inv, acc.w * inv);
}

extern "C" void kernel_launch(void* const* d_in, const int* in_sizes, int n_in,
                              void* d_out, int out_size, void* d_ws, size_t ws_size,
                              hipStream_t stream) {
  const float* q = (const float*)d_in[0];
  const float* k = (const float*)d_in[1];
  const float* v = (const float*)d_in[2];
  const unsigned char* m = (const unsigned char*)d_in[3];
  float* out = (float*)d_out;
  (void)in_sizes; (void)n_in; (void)out_size;

  constexpr size_t OPB = (size_t)NSPLIT * ROWS * Dn * sizeof(__half); // 33.6 MB
  constexpr size_t MLB = (size_t)NSPLIT * ROWS * sizeof(float);       // 512 KB
  constexpr size_t KPB = (size_t)Bn * NKB * TILE_USH * 2;             // 4 MB
  constexpr size_t CNTB = 64;                                          // 8 ints
  constexpr size_t IDXB = (size_t)Bn * Sn * sizeof(unsigned short);   // 32 KB

  char* ws = (char*)d_ws;
  if (ws_size >= OPB + 2 * MLB + 2 * KPB + CNTB + IDXB) {
    __half* Op = (__half*)ws;
    float* Mp = (float*)(ws + OPB);
    float* Lp = (float*)(ws + OPB + MLB);
    unsigned short* Kp = (unsigned short*)(ws + OPB + 2 * MLB);
    unsigned short* Vp = (unsigned short*)(ws + OPB + 2 * MLB + KPB);
    int* cnt = (int*)(ws + OPB + 2 * MLB + 2 * KPB);
    unsigned short* idx = (unsigned short*)(ws + OPB + 2 * MLB + 2 * KPB + CNTB);
    mask_scan<<<dim3(Bn), dim3(256), 0, stream>>>(m, idx, cnt);
    prep<<<dim3(Bn * NKB * 4), dim3(256), 0, stream>>>(k, v, idx, cnt, Kp, Vp);
    attn_fwd<NSPLIT, false><<<dim3(Bn * QT * NSPLIT), dim3(512), 0, stream>>>(
        q, Kp, Vp, cnt, out, Op, Mp, Lp);
    attn_combine<<<dim3(ROWS * 32 / 256), dim3(256), 0, stream>>>(
        Op, Mp, Lp, (float4*)out);
  } else if (ws_size >= 2 * KPB + CNTB + IDXB) {
    unsigned short* Kp = (unsigned short*)ws;
    unsigned short* Vp = (unsigned short*)(ws + KPB);
    int* cnt = (int*)(ws + 2 * KPB);
    unsigned short* idx = (unsigned short*)(ws + 2 * KPB + CNTB);
    mask_scan<<<dim3(Bn), dim3(256), 0, stream>>>(m, idx, cnt);
    prep<<<dim3(Bn * NKB * 4), dim3(256), 0, stream>>>(k, v, idx, cnt, Kp, Vp);
    attn_fwd<1, true><<<dim3(Bn * QT), dim3(512), 0, stream>>>(
        q, Kp, Vp, cnt, out, nullptr, nullptr, nullptr);
  }
}

// Round 10
// 107.993 us; speedup vs baseline: 1.4672x; 1.4672x over previous
//
#include <hip/hip_runtime.h>
#include <hip/hip_fp16.h>
#include <math.h>

typedef __attribute__((ext_vector_type(8))) short short8;
typedef __attribute__((ext_vector_type(16))) float floatx16;
typedef __attribute__((ext_vector_type(2))) __bf16 bf16x2;
typedef __attribute__((ext_vector_type(2))) unsigned int uint2v;

namespace {
constexpr int Bn = 8;
constexpr int Sn = 2048;
constexpr int Dn = 128;
constexpr int BQ = 128;                // queries per block (4 waves x 32)
constexpr int BK = 64;                 // keys per tile
constexpr int QTILES = Sn / BQ;        // 16
constexpr int NKB = Sn / BK;           // 32 (max tiles; compacted count is dynamic)
constexpr int ROWS = Bn * Sn;          // 16384
constexpr int NSPLIT = 4;              // grid 512 blocks(256thr) = 2 blocks/CU
constexpr float SC2 = 0.12753102063642597f;  // (1/sqrt(128)) * log2(e)
constexpr float DEFER_THR = 8.0f;      // log2-domain defer-max threshold (T13)
constexpr int TILE_USH = BK * Dn;      // 8192 ushorts = 16 KB tile
}

#if __has_builtin(__builtin_amdgcn_exp2f)
#define EXP2(x) __builtin_amdgcn_exp2f(x)
#else
#define EXP2(x) exp2f(x)
#endif

__device__ __forceinline__ unsigned short f2bf(float x) {
  union { float f; unsigned u; } a; a.f = x;
  unsigned r = a.u + 0x7fffu + ((a.u >> 16) & 1u);   // RNE
  return (unsigned short)(r >> 16);
}

// HW packed convert: 2 floats -> bf16x2 (v_cvt_pk_bf16_f32)
__device__ __forceinline__ unsigned pack2bf(float x, float y) {
  union { bf16x2 b; unsigned u; } c;
  c.b[0] = (__bf16)x; c.b[1] = (__bf16)y;
  return c.u;
}

// lane[i] <-> lane[i+32] half exchange; returns {r0, r1}:
//   r0[lane<32]=a(own)          r0[lane>=32]=b(from lane-32)
//   r1[lane<32]=a(from lane+32) r1[lane>=32]=b(own)
__device__ __forceinline__ uint2v pl32swap(unsigned a, unsigned b, int h) {
#if __has_builtin(__builtin_amdgcn_permlane32_swap)
  (void)h;
  return __builtin_amdgcn_permlane32_swap(a, b, false, false);
#else
  unsigned ax = __shfl_xor((int)a, 32);
  unsigned bx = __shfl_xor((int)b, 32);
  uint2v r;
  r[0] = h ? bx : a;
  r[1] = h ? b : ax;
  return r;
#endif
}

__device__ __forceinline__ void gl_lds16(const void* g, void* l, int lane) {
#if __has_builtin(__builtin_amdgcn_global_load_lds)
  (void)lane;
  __builtin_amdgcn_global_load_lds((const __attribute__((address_space(1))) unsigned int*)g,
                                   (__attribute__((address_space(3))) unsigned int*)l, 16, 0, 0);
#else
  *(float4*)((char*)l + lane * 16) = *(const float4*)g;
#endif
}

// ---------------- mask scan (8 blocks x 256 thr, one block per batch):
// layout sniff + prefix scan of unmasked keys -> compacted index list
// idx[b][0..cnt), cnt[b]. Bias derived from cnt in-register in attn_fwd.
__global__ __launch_bounds__(256)
void mask_scan(const unsigned char* __restrict__ mraw,
               unsigned short* __restrict__ idxg, int* __restrict__ cntg) {
  __shared__ int sc[256];
  const int b = blockIdx.x;
  const int t = threadIdx.x;

  // sniff dtype of the mask buffer (same first 1 KB for all blocks -> consistent)
  unsigned wv = ((const unsigned int*)mraw)[t];
  int any1  = __syncthreads_or((wv & 0x0000ff00u) ? 1 : 0);
  int any23 = __syncthreads_or((wv & 0xffff0000u) ? 1 : 0);
  const int mlayout = any1 ? 1 : (any23 ? 2 : 0);

  const int s0 = t * 8;              // 8 consecutive key positions per thread
  const int gbase = b * Sn + s0;
  bool ms[8];
  if (mlayout == 1) {
    #pragma unroll
    for (int i = 0; i < 8; ++i) ms[i] = mraw[gbase + i] != 0;
  } else if (mlayout == 2) {
    const float* mf = (const float*)mraw;
    #pragma unroll
    for (int i = 0; i < 8; ++i) ms[i] = mf[gbase + i] != 0.0f;
  } else {
    const int* mi = (const int*)mraw;
    #pragma unroll
    for (int i = 0; i < 8; ++i) ms[i] = mi[gbase + i] != 0;
  }

  int c = 0;
  #pragma unroll
  for (int i = 0; i < 8; ++i) c += ms[i] ? 0 : 1;
  sc[t] = c;
  __syncthreads();
  for (int off = 1; off < 256; off <<= 1) {      // Hillis-Steele inclusive scan
    int v = (t >= off) ? sc[t - off] : 0;
    __syncthreads();
    sc[t] += v;
    __syncthreads();
  }
  const int incl = sc[t];
  const int total = sc[255];
  int pos = incl - c;                            // exclusive prefix
  #pragma unroll
  for (int i = 0; i < 8; ++i)
    if (!ms[i]) idxg[b * Sn + (pos++)] = (unsigned short)(s0 + i);
  if (t == 0) cntg[b] = total;
}

// ---------------- pre-pass (1024 blocks x 256 thr, 16 compacted slots each):
// gather unmasked K/V rows through idx; K -> bf16 swizzled tiles
// [key][oct(d>>3)^(key&7)], V -> bf16 transposed tiles [d][oct(key>>3)^(d&7)].
// Padding slots (cnt..padded) are ZEROED. Blocks beyond padded end early-out.
__global__ __launch_bounds__(256)
void prep(const float* __restrict__ kg, const float* __restrict__ vg,
          const unsigned short* __restrict__ idxg, const int* __restrict__ cntg,
          unsigned short* __restrict__ Kpg, unsigned short* __restrict__ Vpg) {
  __shared__ __align__(16) float Vf[16 * 136];
  const int p = blockIdx.x;
  const int b = p >> 7, qq = p & 127;
  const int kb = qq >> 2, k16 = qq & 3;
  const int t = threadIdx.x;

  const int cnt = cntg[b];
  const int padded = (cnt + 63) & ~63;
  const int slot0 = kb * 64 + k16 * 16;
  if (slot0 >= padded) return;                   // block-uniform

  const int j  = t >> 4;
  const int o8 = t & 15;
  const int sl = slot0 + j;
  const bool real = sl < cnt;

  float4 a, bq, va, vb;
  if (real) {
    const int srow = idxg[b * Sn + sl];
    const size_t base = ((size_t)(b * Sn + srow)) * 32 + o8 * 2;
    a  = ((const float4*)kg)[base]; bq = ((const float4*)kg)[base + 1];
    va = ((const float4*)vg)[base]; vb = ((const float4*)vg)[base + 1];
  } else {
    a = bq = va = vb = make_float4(0.f, 0.f, 0.f, 0.f);
  }

  {
    union { unsigned u[4]; short8 s8; } pk;
    pk.u[0] = pack2bf(a.x, a.y);   pk.u[1] = pack2bf(a.z, a.w);
    pk.u[2] = pack2bf(bq.x, bq.y); pk.u[3] = pack2bf(bq.z, bq.w);
    const int jl = k16 * 16 + j;
    *(short8*)(Kpg + (size_t)(b * NKB + kb) * TILE_USH + jl * 128 + ((o8 ^ (jl & 7)) * 8)) = pk.s8;
  }
  {
    *(float4*)&Vf[j * 136 + o8 * 8]     = va;
    *(float4*)&Vf[j * 136 + o8 * 8 + 4] = vb;
  }
  __syncthreads();
  {
    const int d = t >> 1, h = t & 1;
    union { unsigned u[4]; short8 s8; } pv;
    #pragma unroll
    for (int i = 0; i < 4; ++i)
      pv.u[i] = pack2bf(Vf[(h * 8 + 2 * i) * 136 + d], Vf[(h * 8 + 2 * i + 1) * 136 + d]);
    const int og = k16 * 2 + h;
    *(short8*)(Vpg + (size_t)(b * NKB + kb) * TILE_USH + d * 64 + ((og ^ (d & 7)) * 8)) = pv.s8;
  }
}

// ---- staging helper: one wave stages its 4 KB quarter of a 16 KB tile ----
__device__ __forceinline__ void stage_tile(const char* gsrc, char* ldst,
                                           int stagebase, int L) {
  #pragma unroll
  for (int i = 0; i < 4; ++i) {
    const int off = stagebase + i * 1024;
    gl_lds16(gsrc + off + L * 16, ldst + off, L);
  }
}

// ---------------- main flash kernel over COMPACTED keys.
// R10: SINGLE barrier per tile (R8 had two). Key change: stage-issue moved to
// AFTER B1(i). Once all waves pass B1(i), every wave has finished tile i-1's
// reads (they precede B1 in program order), so overwriting the i-1 buffers
// (K dest (i+2)%3 == (i-1)%3, V dest (i+1)&1 == (i-1)&1) is race-free with
// NO trailing barrier. Stages still fly 1-2 tiles ahead; counted vmcnt (T4)
// keeps them in flight across barriers.
//   per tile: s_waitcnt vmcnt(4|0) -> s_barrier -> issue V(i+1),K(i+2)
//             -> compute tile i from LDS.
// vmcnt FIFO check (interior): outstanding at the wait = [K(i) from iter i-2,
// V(i) from iter i-1, K(i+1) from iter i-1]; need K(i),V(i) -> vmcnt(4) leaves
// only the newest 4 (K(i+1)). Tail: vmcnt(0). Verified for T=1..5.
// (R9 lesson: 4 waves/SIMD forces <=128 total regs incl. accumulators ->
// massive spill (VGPR_Count 64, +120 MB scratch). 2 waves/SIMD is the ceiling
// for this 32-query/wave structure; geometry stays 256thr/(256,2).)
template<int SPLIT, bool DIRECT>
__global__ __launch_bounds__(256, 2)
void attn_fwd(const float* __restrict__ qg,
              const unsigned short* __restrict__ Kpg,
              const unsigned short* __restrict__ Vpg,
              const int* __restrict__ cntg,
              float* __restrict__ outg, __half* __restrict__ Op,
              float* __restrict__ Mp, float* __restrict__ Lp) {
  __shared__ __align__(16) unsigned short Khi[3][TILE_USH];  // 49152 B
  __shared__ __align__(16) unsigned short Vt[2][TILE_USH];   // 32768 B
  // total 81920 B -> exactly 2 blocks/CU (160 KB LDS)

  const int tid = threadIdx.x;
  const int bid = blockIdx.x;
  const int b   = bid & 7;                       // batch -> XCD swizzle
  const int q0  = ((bid >> 3) & (QTILES - 1)) * BQ;
  const int s   = bid >> 7;                      // split index (0 when SPLIT==1)
  const int w   = tid >> 6;                      // wave 0..3
  const int L   = tid & 63;
  const int q   = L & 31;                        // query within wave
  const int h   = L >> 5;                        // k-half selector
  const int sw  = q & 7;                         // octet XOR swizzle key

  const int cnt = cntg[b];
  const int nt  = (cnt + 63) >> 6;               // compacted tile count
  const int kb0 = (s * nt) / SPLIT;
  const int kbN = ((s + 1) * nt) / SPLIT;
  const int T   = kbN - kb0;

  const int row = b * Sn + q0 + w * 32 + q;

  if (T <= 0) {                                  // empty split: zero partials
    if constexpr (DIRECT) {
      float* orow = outg + (size_t)row * Dn;
      float4 z = make_float4(0.f, 0.f, 0.f, 0.f);
      #pragma unroll
      for (int dg = 0; dg < 4; ++dg)
        #pragma unroll
        for (int ro = 0; ro < 4; ++ro) *(float4*)&orow[dg * 32 + 8 * ro + 4 * h] = z;
    } else {
      __half* orow = Op + ((size_t)s * ROWS + row) * Dn;
      uint2 z; z.x = 0u; z.y = 0u;
      #pragma unroll
      for (int dg = 0; dg < 4; ++dg)
        #pragma unroll
        for (int ro = 0; ro < 4; ++ro) *(uint2*)&orow[dg * 32 + 8 * ro + 4 * h] = z;
      if (h == 0) { Mp[s * ROWS + row] = -INFINITY; Lp[s * ROWS + row] = 0.0f; }
    }
    return;
  }

  const char* ktile = (const char*)(Kpg + (size_t)b * NKB * TILE_USH);
  const char* vtile = (const char*)(Vpg + (size_t)b * NKB * TILE_USH);
  const int stagebase = w * 4096;                // wave's quarter of a 16 KB tile

  // Q B-fragments: lane holds Q[row q][d = kstep*16 + h*8 + j], hi/lo split
  short8 qh[8], ql[8];
  {
    const float* qrow = qg + (size_t)row * Dn;
    #pragma unroll
    for (int kstep = 0; kstep < 8; ++kstep) {
      float4 f0 = *(const float4*)(qrow + kstep * 16 + h * 8);
      float4 f1 = *(const float4*)(qrow + kstep * 16 + h * 8 + 4);
      float xs[8] = {f0.x, f0.y, f0.z, f0.w, f1.x, f1.y, f1.z, f1.w};
      #pragma unroll
      for (int j = 0; j < 8; ++j) {
        unsigned short hi = f2bf(xs[j]);
        union { unsigned u; float f; } hv; hv.u = ((unsigned)hi) << 16;
        qh[kstep][j] = (short)hi;
        ql[kstep][j] = (short)f2bf(xs[j] - hv.f);
      }
    }
  }

  float m_i = -INFINITY, l_i = 0.0f;
  float mtrue = -INFINITY;
  floatx16 O32[4];
  #pragma unroll
  for (int dg = 0; dg < 4; ++dg)
    #pragma unroll
    for (int r = 0; r < 16; ++r) O32[dg][r] = 0.0f;

  // ---- prologue: issue V(0), K(0), K(1) (FIFO order matters for vmcnt) ----
  stage_tile(vtile + (size_t)kb0 * (TILE_USH * 2), (char*)Vt[0], stagebase, L);
  stage_tile(ktile + (size_t)kb0 * (TILE_USH * 2), (char*)Khi[0], stagebase, L);
  if (kb0 + 1 < kbN)
    stage_tile(ktile + (size_t)(kb0 + 1) * (TILE_USH * 2), (char*)Khi[1], stagebase, L);

  int ci3 = 0;                                   // i % 3 (K buffer index)
  for (int kb = kb0; kb < kbN; ++kb) {
    const int i = kb - kb0;

    // ---- counted wait: tile-i V,K done; newer K(i+1) may stay in flight ----
    if (kb + 1 < kbN) asm volatile("s_waitcnt vmcnt(4)" ::: "memory");
    else              asm volatile("s_waitcnt vmcnt(0)" ::: "memory");
    __builtin_amdgcn_s_barrier();   // B1: tile-i data ready AND all waves done
    asm volatile("" ::: "memory");  //     with tile i-1 reads (program order)

    // ---- issue next stages AFTER the barrier: overwrites i-1 buffers, safe ----
    if (kb + 1 < kbN)
      stage_tile(vtile + (size_t)(kb + 1) * (TILE_USH * 2),
                 (char*)Vt[(i + 1) & 1], stagebase, L);
    int nk3 = ci3 + 2; if (nk3 >= 3) nk3 -= 3;
    if (kb + 2 < kbN)
      stage_tile(ktile + (size_t)(kb + 2) * (TILE_USH * 2),
                 (char*)Khi[nk3], stagebase, L);

    const unsigned short* Kc = Khi[ci3];
    const unsigned short* Vc = Vt[i & 1];

    // ---- S^T = K * Q^T : 2 key-groups x 8 ksteps, hi+lo (K from LDS) ----
    floatx16 sS[2];
    #pragma unroll
    for (int kg = 0; kg < 2; ++kg)
      #pragma unroll
      for (int r = 0; r < 16; ++r) sS[kg][r] = 0.0f;
    #pragma unroll
    for (int kstep = 0; kstep < 8; ++kstep) {
      const int ko = ((kstep * 2 + h) ^ sw) * 8;
      #pragma unroll
      for (int kg = 0; kg < 2; ++kg) {
        short8 kf = *(const short8*)&Kc[(kg * 32 + q) * 128 + ko];
        sS[kg] = __builtin_amdgcn_mfma_f32_32x32x16_bf16(kf, qh[kstep], sS[kg], 0, 0, 0);
        sS[kg] = __builtin_amdgcn_mfma_f32_32x32x16_bf16(kf, ql[kstep], sS[kg], 0, 0, 0);
      }
    }

    // ---- softmax: scale (+ in-register bias on the last, partial tile) ----
    if ((kb + 1) * BK <= cnt) {                  // full tile (wave-uniform)
      #pragma unroll
      for (int kg = 0; kg < 2; ++kg)
        #pragma unroll
        for (int r = 0; r < 16; ++r) sS[kg][r] *= SC2;
    } else {
      #pragma unroll
      for (int kg = 0; kg < 2; ++kg)
        #pragma unroll
        for (int r = 0; r < 16; ++r) {
          const int key = kb * BK + kg * 32 + ((r & 3) + 8 * (r >> 2)) + 4 * h;
          sS[kg][r] = fmaf(sS[kg][r], SC2, (key < cnt) ? 0.0f : -1e30f);
        }
    }
    float mxp[4] = {-INFINITY, -INFINITY, -INFINITY, -INFINITY};
    #pragma unroll
    for (int kg = 0; kg < 2; ++kg)
      #pragma unroll
      for (int r = 0; r < 16; ++r) mxp[r & 3] = fmaxf(mxp[r & 3], sS[kg][r]);
    float mx = fmaxf(fmaxf(mxp[0], mxp[1]), fmaxf(mxp[2], mxp[3]));
    mx = fmaxf(mx, __shfl_xor(mx, 32));
    mtrue = fmaxf(mtrue, mx);

    float mnew;
    if (__all(mx <= m_i + DEFER_THR)) {
      mnew = m_i;                       // T13: defer; P bounded by 2^THR
    } else {
      mnew = fmaxf(m_i, mx);
      const float alpha = EXP2(m_i - mnew);   // 0 when m_i == -inf
      l_i *= alpha;
      #pragma unroll
      for (int dg = 0; dg < 4; ++dg)
        #pragma unroll
        for (int r = 0; r < 16; ++r) O32[dg][r] *= alpha;
    }

    float rsp[4] = {0.f, 0.f, 0.f, 0.f};
    #pragma unroll
    for (int kg = 0; kg < 2; ++kg)
      #pragma unroll
      for (int r = 0; r < 16; ++r) {
        float e = EXP2(sS[kg][r] - mnew);
        sS[kg][r] = e;
        rsp[r & 3] += e;
      }
    float rs = (rsp[0] + rsp[1]) + (rsp[2] + rsp[3]);
    rs += __shfl_xor(rs, 32);
    l_i += rs;
    m_i = mnew;

    // ---- T12: P -> bf16 in-register, half-exchange via permlane32_swap ----
    unsigned xw[2][4][2];
    #pragma unroll
    for (int kg = 0; kg < 2; ++kg)
      #pragma unroll
      for (int m = 0; m < 4; ++m) {
        xw[kg][m][0] = pack2bf(sS[kg][4 * m + 0], sS[kg][4 * m + 1]);
        xw[kg][m][1] = pack2bf(sS[kg][4 * m + 2], sS[kg][4 * m + 3]);
      }
    unsigned pfw[4][4];
    #pragma unroll
    for (int kg = 0; kg < 2; ++kg)
      #pragma unroll
      for (int j = 0; j < 2; ++j)
        #pragma unroll
        for (int c2 = 0; c2 < 2; ++c2) {
          uint2v r = pl32swap(xw[kg][2 * j][c2], xw[kg][2 * j + 1][c2], h);
          pfw[kg * 2 + j][c2]     = r[0];   // keys 8s+{2c2,2c2+1}
          pfw[kg * 2 + j][2 + c2] = r[1];   // keys 8s+4+{2c2,2c2+1}
        }

    // ---- O^T += V^T * P^T : 4 ksteps x 4 d-groups (V from LDS) ----
    #pragma unroll
    for (int k2 = 0; k2 < 4; ++k2) {
      const int ko = ((k2 * 2 + h) ^ sw) * 8;
      union { unsigned u[4]; short8 s8; } pw;
      pw.u[0] = pfw[k2][0]; pw.u[1] = pfw[k2][1];
      pw.u[2] = pfw[k2][2]; pw.u[3] = pfw[k2][3];
      #pragma unroll
      for (int dg = 0; dg < 4; ++dg) {
        short8 vf = *(const short8*)&Vc[(dg * 32 + q) * 64 + ko];
        O32[dg] = __builtin_amdgcn_mfma_f32_32x32x16_bf16(vf, pw.s8, O32[dg], 0, 0, 0);
      }
    }

    ci3 = (ci3 == 2) ? 0 : ci3 + 1;
  }

  // ---- epilogue: lane holds out^T[d = dg*32+(r&3)+8*(r>>2)+4h][q] ----
  if constexpr (DIRECT) {
    const float inv = 1.0f / l_i;
    float* orow = outg + (size_t)row * Dn;
    #pragma unroll
    for (int dg = 0; dg < 4; ++dg)
      #pragma unroll
      for (int ro = 0; ro < 4; ++ro) {
        float4 f = make_float4(O32[dg][4 * ro] * inv,     O32[dg][4 * ro + 1] * inv,
                               O32[dg][4 * ro + 2] * inv, O32[dg][4 * ro + 3] * inv);
        *(float4*)&orow[dg * 32 + 8 * ro + 4 * h] = f;
      }
  } else {
    const float fin = EXP2(m_i - mtrue);   // <= 1; ==1 when never deferred
    __half* orow = Op + ((size_t)s * ROWS + row) * Dn;
    #pragma unroll
    for (int dg = 0; dg < 4; ++dg)
      #pragma unroll
      for (int ro = 0; ro < 4; ++ro) {
        union { __half2 h2[2]; uint2 u; } pk;
        pk.h2[0] = __floats2half2_rn(O32[dg][4 * ro] * fin,     O32[dg][4 * ro + 1] * fin);
        pk.h2[1] = __floats2half2_rn(O32[dg][4 * ro + 2] * fin, O32[dg][4 * ro + 3] * fin);
        *(uint2*)&orow[dg * 32 + 8 * ro + 4 * h] = pk.u;
      }
    if (h == 0) {
      Mp[s * ROWS + row] = mtrue;
      Lp[s * ROWS + row] = l_i * fin;
    }
  }
}

// Merge NSPLIT fp16 partials (m in log2 domain): O = sum O_s*2^{m_s-m}; out = O/l.
// Empty splits carry Mp=-inf, Lp=0, Op=0 -> wgt 0, contribute nothing.
__global__ __launch_bounds__(256)
void attn_combine(const __half* __restrict__ Op, const float* __restrict__ Mp,
                  const float* __restrict__ Lp, float4* __restrict__ out4) {
  const int gid = blockIdx.x * 256 + threadIdx.x;
  const int row = gid >> 5;
  const int c4  = gid & 31;
  float ms[NSPLIT];
  float m = -INFINITY;
  #pragma unroll
  for (int s = 0; s < NSPLIT; ++s) { ms[s] = Mp[s * ROWS + row]; m = fmaxf(m, ms[s]); }
  float l = 0.0f;
  float4 acc = make_float4(0.f, 0.f, 0.f, 0.f);
  #pragma unroll
  for (int s = 0; s < NSPLIT; ++s) {
    float wgt = EXP2(ms[s] - m);
    l = fmaf(Lp[s * ROWS + row], wgt, l);
    union { uint2 u; __half2 h2[2]; } pk;
    pk.u = ((const uint2*)Op)[(size_t)(s * ROWS + row) * 32 + c4];
    float2 f0 = __half22float2(pk.h2[0]);
    float2 f1 = __half22float2(pk.h2[1]);
    acc.x = fmaf(f0.x, wgt, acc.x);
    acc.y = fmaf(f0.y, wgt, acc.y);
    acc.z = fmaf(f1.x, wgt, acc.z);
    acc.w = fmaf(f1.y, wgt, acc.w);
  }
  float inv = 1.0f / l;
  out4[(size_t)row * 32 + c4] = make_float4(acc.x * inv, acc.y * inv, acc.z * inv, acc.w * inv);
}

extern "C" void kernel_launch(void* const* d_in, const int* in_sizes, int n_in,
                              void* d_out, int out_size, void* d_ws, size_t ws_size,
                              hipStream_t stream) {
  const float* q = (const float*)d_in[0];
  const float* k = (const float*)d_in[1];
  const float* v = (const float*)d_in[2];
  const unsigned char* m = (const unsigned char*)d_in[3];
  float* out = (float*)d_out;
  (void)in_sizes; (void)n_in; (void)out_size;

  constexpr size_t OPB = (size_t)NSPLIT * ROWS * Dn * sizeof(__half); // 16.8 MB
  constexpr size_t MLB = (size_t)NSPLIT * ROWS * sizeof(float);       // 256 KB
  constexpr size_t KPB = (size_t)Bn * NKB * TILE_USH * 2;             // 4 MB
  constexpr size_t CNTB = 64;                                          // 8 ints
  constexpr size_t IDXB = (size_t)Bn * Sn * sizeof(unsigned short);   // 32 KB

  char* ws = (char*)d_ws;
  if (ws_size >= OPB + 2 * MLB + 2 * KPB + CNTB + IDXB) {
    __half* Op = (__half*)ws;
    float* Mp = (float*)(ws + OPB);
    float* Lp = (float*)(ws + OPB + MLB);
    unsigned short* Kp = (unsigned short*)(ws + OPB + 2 * MLB);
    unsigned short* Vp = (unsigned short*)(ws + OPB + 2 * MLB + KPB);
    int* cnt = (int*)(ws + OPB + 2 * MLB + 2 * KPB);
    unsigned short* idx = (unsigned short*)(ws + OPB + 2 * MLB + 2 * KPB + CNTB);
    mask_scan<<<dim3(Bn), dim3(256), 0, stream>>>(m, idx, cnt);
    prep<<<dim3(Bn * NKB * 4), dim3(256), 0, stream>>>(k, v, idx, cnt, Kp, Vp);
    attn_fwd<NSPLIT, false><<<dim3(Bn * QTILES * NSPLIT), dim3(256), 0, stream>>>(
        q, Kp, Vp, cnt, out, Op, Mp, Lp);
    attn_combine<<<dim3(ROWS * 32 / 256), dim3(256), 0, stream>>>(
        Op, Mp, Lp, (float4*)out);
  } else if (ws_size >= 2 * KPB + CNTB + IDXB) {
    unsigned short* Kp = (unsigned short*)ws;
    unsigned short* Vp = (unsigned short*)(ws + KPB);
    int* cnt = (int*)(ws + 2 * KPB);
    unsigned short* idx = (unsigned short*)(ws + 2 * KPB + CNTB);
    mask_scan<<<dim3(Bn), dim3(256), 0, stream>>>(m, idx, cnt);
    prep<<<dim3(Bn * NKB * 4), dim3(256), 0, stream>>>(k, v, idx, cnt, Kp, Vp);
    attn_fwd<1, true><<<dim3(Bn * QTILES), dim3(256), 0, stream>>>(
        q, Kp, Vp, cnt, out, nullptr, nullptr, nullptr);
  }
}